// Round 7
// baseline (114.573 us; speedup 1.0000x reference)
//
#include <hip/hip_runtime.h>

typedef __attribute__((ext_vector_type(8))) short bf16x8;
typedef __attribute__((ext_vector_type(4))) float f32x4;
typedef __attribute__((ext_vector_type(4))) unsigned int u32x4;
typedef unsigned short u16;

#define MFMA16(a,b,c) __builtin_amdgcn_mfma_f32_16x16x32_bf16((a),(b),(c),0,0,0)

__device__ __forceinline__ u16 f2bf(float f){
  unsigned int u = __float_as_uint(f);
  u += 0x7fffu + ((u >> 16) & 1u);
  return (u16)(u >> 16);
}
__device__ __forceinline__ float bf2f(u16 v){
  return __uint_as_float(((unsigned int)v) << 16);
}
__device__ __forceinline__ unsigned int cvtpk(float lo, float hi){
  unsigned int r;
  asm("v_cvt_pk_bf16_f32 %0, %1, %2" : "=v"(r) : "v"(lo), "v"(hi));
  return r;
}
__device__ __forceinline__ void gload16(const void* g, void* l){
  __builtin_amdgcn_global_load_lds(
      (__attribute__((address_space(1))) void*)g,
      (__attribute__((address_space(3))) void*)l, 16, 0, 0);
}

// ---------------- prepass: fp32 -> bf16 flat convert ----------------
__global__ __launch_bounds__(256) void mqa_cvt(const float* __restrict__ in,
                                               u16* __restrict__ out, int n8){
  int i = blockIdx.x * 256 + threadIdx.x;
  if (i >= n8) return;
  const float4* p = (const float4*)in;
  float4 a = p[2*i], b = p[2*i+1];
  u16 o[8] = { f2bf(a.x), f2bf(a.y), f2bf(a.z), f2bf(a.w),
               f2bf(b.x), f2bf(b.y), f2bf(b.z), f2bf(b.w) };
  *(bf16x8*)&out[(size_t)i*8] = *(bf16x8*)o;
}

// ---------------- prepass: all 4 weight transposes in ONE launch ----------
__global__ __launch_bounds__(256) void mqa_tcvt4(
    const float* __restrict__ Wq, const float* __restrict__ Wk,
    const float* __restrict__ Wv, const float* __restrict__ Wo,
    u16* __restrict__ WT, u16* __restrict__ WoT)
{
  __shared__ float t[32][33];
  int bx = blockIdx.x;
  const float* src; u16* dst; int C, cb, rb;
  if (bx < 1024)      { src = Wq; dst = WT;                      C = 1024; int q = bx;        cb = q & 31; rb = q >> 5; }
  else if (bx < 1088) { src = Wk; dst = WT + (size_t)1024*1024;  C = 64;   int q = bx - 1024; cb = q & 1;  rb = q >> 1; }
  else if (bx < 1152) { src = Wv; dst = WT + (size_t)1088*1024;  C = 64;   int q = bx - 1088; cb = q & 1;  rb = q >> 1; }
  else                { src = Wo; dst = WoT;                     C = 1024; int q = bx - 1152; cb = q & 31; rb = q >> 5; }
  int c0 = cb * 32, r0 = rb * 32;
  int x = threadIdx.x & 31, y0 = threadIdx.x >> 5;
  #pragma unroll
  for (int yy = y0; yy < 32; yy += 8)
    t[yy][x] = src[(size_t)(r0 + yy) * C + c0 + x];
  __syncthreads();
  #pragma unroll
  for (int yy = y0; yy < 32; yy += 8)
    dst[(size_t)(c0 + yy) * 1024 + r0 + x] = f2bf(t[x][yy]);
}

// ---------------- GEMM: A[M][K] bf16 row-major, Bt[N][K] bf16 row-major ----
// BM=64, BN=128, double-buffered LDS with ONE barrier per K-step so the
// next tile's global_load_lds latency hides under this tile's compute.
// EPI 0: fp32 out.  EPI 1: QKV scatter (V k-permuted, bits [k5 k3 k2 k4 k1 k0]).
template<int EPI>
__global__ __launch_bounds__(256, 4) void mqa_gemm(
    const u16* __restrict__ A, const u16* __restrict__ Bt,
    float* __restrict__ outF, u16* __restrict__ Qb, u16* __restrict__ Kb,
    u16* __restrict__ Vtb, int M, int N, int K, int NT)
{
  __shared__ __align__(16) u16 lds_a[2][64*32];
  __shared__ __align__(16) u16 lds_b[2][128*32];
  int bx = blockIdx.x;
  int mt = bx / NT, nt = bx % NT;
  int m0 = mt * 64, n0 = nt * 128;
  int tid = threadIdx.x;
  int wid = tid >> 6, lane = tid & 63;
  int wr = (wid >> 1) * 32, wc = (wid & 1) * 64;
  int lrow = lane >> 2;          // staging: row within 16-row chunk
  int lk   = (lane & 3) * 8;     // staging: k offset (8 bf16 = 16B)
  int fr = lane & 15, g8 = (lane >> 4) * 8, fg = lane >> 4;

  f32x4 acc[2][4];
  #pragma unroll
  for (int i = 0; i < 2; ++i)
    #pragma unroll
    for (int j = 0; j < 4; ++j) acc[i][j] = (f32x4)0.f;

  // stage one 64x32 A + 128x32 B tile into buffer `bi`
  auto stage = [&](int bi, int k0){
    #pragma unroll
    for (int cc = 0; cc < 3; ++cc) {
      int c = 3*wid + cc;
      if (c < 4) gload16(&A [(size_t)(m0 + c*16 + lrow) * K + k0 + lk], &lds_a[bi][c*512]);
      else       gload16(&Bt[(size_t)(n0 + (c-4)*16 + lrow) * K + k0 + lk], &lds_b[bi][(c-4)*512]);
    }
  };

  stage(0, 0);
  __syncthreads();
  int cur = 0;
  for (int k0 = 0; k0 < K; k0 += 32) {
    if (k0 + 32 < K) stage(cur ^ 1, k0 + 32);
    bf16x8 af[2], bfr[4];
    #pragma unroll
    for (int i = 0; i < 2; ++i) af[i] = *(const bf16x8*)&lds_a[cur][(wr + i*16 + fr)*32 + g8];
    #pragma unroll
    for (int j = 0; j < 4; ++j) bfr[j] = *(const bf16x8*)&lds_b[cur][(wc + j*16 + fr)*32 + g8];
    #pragma unroll
    for (int i = 0; i < 2; ++i)
      #pragma unroll
      for (int j = 0; j < 4; ++j)
        acc[i][j] = MFMA16(af[i], bfr[j], acc[i][j]);
    __syncthreads();   // drains vmcnt: next buffer staged; this buffer read-done
    cur ^= 1;
  }

  #pragma unroll
  for (int i = 0; i < 2; ++i) {
    #pragma unroll
    for (int j = 0; j < 4; ++j) {
      int ncol = n0 + wc + j*16 + fr;
      #pragma unroll
      for (int r = 0; r < 4; ++r) {
        int m = m0 + wr + i*16 + fg*4 + r;
        float v = acc[i][j][r];
        if (EPI == 0) {
          outF[(size_t)m * N + ncol] = v;
        } else {
          u16 bv = f2bf(v);
          if (ncol < 1024) {
            Qb[(size_t)m * 1024 + ncol] = bv;              // Q [B,S,H*HD]
          } else if (ncol < 1088) {
            Kb[(size_t)m * 64 + (ncol - 1024)] = bv;       // K [B,S,HD]
          } else {
            int b = m >> 11, s = m & 2047;                 // Vp [B,HD,S-perm]
            int k = s & 63;
            int pos = (k & 35) | ((k & 12) << 1) | ((k & 16) >> 2);
            Vtb[((size_t)b * 64 + (ncol - 1088)) * 2048 + (s & ~63) + pos] = bv;
          }
        }
      }
    }
  }
}

// ---------------- flash MQA attention ----------------
// swapped-QK^T (P in-register), FIXED-MAX softmax, 64 q-rows per wave
// (qf=4: halves per-q LDS traffic), K/V double-buffered LDS via
// global_load_lds (XOR-swizzled source), KV-split x2.
// grid (S/256, H, B*2); z = b*2+sp covers keys [sp*1024,+1024).
__global__ __launch_bounds__(256, 2) void mqa_attn(
    const u16* __restrict__ Qb, const u16* __restrict__ Kb,
    const u16* __restrict__ Vtb, u16* __restrict__ Opart,
    float* __restrict__ Lpart)
{
  const float C1 = 0.18033688011112042f;  // (1/8) * log2(e)
  const float MC = 32.f * C1;             // fixed max: raw score 32 (~9.4 sigma)
  int qt = blockIdx.x, h = blockIdx.y;
  int b = blockIdx.z >> 1, sp = blockIdx.z & 1;
  int part = blockIdx.z;
  int tid = threadIdx.x, wid = tid >> 6, lane = tid & 63;
  int fr = lane & 15, g = lane >> 4;
  int q0 = qt * 256 + wid * 64;

  // [buf][64 rows][64 cols] bf16, 8KB each; cols stored col16^(row&7) swizzled
  __shared__ __align__(16) u16 KT[2][64*64];
  __shared__ __align__(16) u16 VT[2][64*64];

  const u16* Qbase = Qb + (size_t)b * 2048 * 1024 + (size_t)h * 64;
  const u16* Kbase = Kb + (size_t)b * 2048 * 64;
  const u16* Vbase = Vtb + (size_t)b * 64 * 2048;

  // staging: wave stages rows [wid*16,+16) via 2 instrs (8 rows each);
  // lane l -> row_in_8 = l>>3, src col16 = (l&7)^(l>>3)  (dest is linear)
  int srow = lane >> 3;
  int scol = ((lane & 7) ^ srow) * 8;

  // Q as the MFMA B-operand: lane(fr,g) slot j = Q[q = qf*16+fr][d = ks*32+g*8+j]
  bf16x8 qfv[4][2];
  #pragma unroll
  for (int qf_ = 0; qf_ < 4; ++qf_)
    #pragma unroll
    for (int ks = 0; ks < 2; ++ks)
      qfv[qf_][ks] = *(const bf16x8*)&Qbase[(size_t)(q0 + qf_*16 + fr) * 1024 + ks*32 + g*8];

  f32x4 oacc[4][4];
  #pragma unroll
  for (int qf_ = 0; qf_ < 4; ++qf_)
    #pragma unroll
    for (int vf = 0; vf < 4; ++vf) oacc[qf_][vf] = (f32x4)0.f;
  float lacc[4] = {0.f, 0.f, 0.f, 0.f};

  const int kb0 = sp * 16;

  // prologue: stage tile kb0 into buf 0
  #pragma unroll
  for (int j = 0; j < 2; ++j) {
    int row = wid*16 + j*8 + srow;
    gload16(&Kbase[(size_t)(kb0*64 + row) * 64 + scol], &KT[0][(wid*16 + j*8) * 64]);
    gload16(&Vbase[(size_t)row * 2048 + kb0*64 + scol], &VT[0][(wid*16 + j*8) * 64]);
  }
  __syncthreads();

  int cur = 0;
  for (int kb = kb0; kb < kb0 + 16; ++kb) {
    // stage next tile into buf cur^1 (last iter: harmless re-stage of kb0)
    int ntl = (kb + 1 < kb0 + 16) ? kb + 1 : kb0;
    #pragma unroll
    for (int j = 0; j < 2; ++j) {
      int row = wid*16 + j*8 + srow;
      gload16(&Kbase[(size_t)(ntl*64 + row) * 64 + scol], &KT[cur^1][(wid*16 + j*8) * 64]);
      gload16(&Vbase[(size_t)row * 2048 + ntl*64 + scol], &VT[cur^1][(wid*16 + j*8) * 64]);
    }

    const u16* kc = &KT[cur][0];
    const u16* vc = &VT[cur][0];

    f32x4 sacc[4][4];
    #pragma unroll
    for (int qf_ = 0; qf_ < 4; ++qf_)
      #pragma unroll
      for (int kf = 0; kf < 4; ++kf) sacc[qf_][kf] = (f32x4)0.f;

    // S^T = K Q^T : lane(fr,g) gets S[k = kf*16+g*4+r][q = qf*16+fr]
    __builtin_amdgcn_s_setprio(1);
    #pragma unroll
    for (int ks = 0; ks < 2; ++ks) {
      #pragma unroll
      for (int kf = 0; kf < 4; ++kf) {
        bf16x8 kfr = *(const bf16x8*)&kc[(kf*16 + fr)*64 + (((ks*4+g) ^ (fr&7)))*8];
        #pragma unroll
        for (int qf_ = 0; qf_ < 4; ++qf_)
          sacc[qf_][kf] = MFMA16(kfr, qfv[qf_][ks], sacc[qf_][kf]);
      }
    }
    __builtin_amdgcn_s_setprio(0);

    // V fragments for this tile (shared across all 4 qf)
    bf16x8 vfr[8];
    #pragma unroll
    for (int i = 0; i < 8; ++i) {
      int ks2 = i >> 2, vf = i & 3;
      vfr[i] = *(const bf16x8*)&vc[(vf*16 + fr)*64 + (((ks2*4+g) ^ (fr&7)))*8];
    }

    // per qf: P = exp2(s*C1 - MC) -> packed bf16 A-frags -> PV MFMAs
    #pragma unroll
    for (int qf_ = 0; qf_ < 4; ++qf_) {
      unsigned int pk[8];
      float s0 = 0.f;
      #pragma unroll
      for (int kf = 0; kf < 4; ++kf) {
        float a0 = __builtin_amdgcn_exp2f(sacc[qf_][kf][0] * C1 - MC);
        float a1 = __builtin_amdgcn_exp2f(sacc[qf_][kf][1] * C1 - MC);
        float a2 = __builtin_amdgcn_exp2f(sacc[qf_][kf][2] * C1 - MC);
        float a3 = __builtin_amdgcn_exp2f(sacc[qf_][kf][3] * C1 - MC);
        s0 += (a0 + a1) + (a2 + a3);
        pk[2*kf]   = cvtpk(a0, a1);
        pk[2*kf+1] = cvtpk(a2, a3);
      }
      lacc[qf_] += s0;

      __builtin_amdgcn_s_setprio(1);
      #pragma unroll
      for (int ks2 = 0; ks2 < 2; ++ks2) {
        u32x4 w = { pk[4*ks2], pk[4*ks2+1], pk[4*ks2+2], pk[4*ks2+3] };
        bf16x8 pA = __builtin_bit_cast(bf16x8, w);
        #pragma unroll
        for (int vf = 0; vf < 4; ++vf)
          oacc[qf_][vf] = MFMA16(pA, vfr[ks2*4+vf], oacc[qf_][vf]);
      }
      __builtin_amdgcn_s_setprio(0);
    }

    __syncthreads();   // drains vmcnt(0): next tile staged; buf reads done
    cur ^= 1;
  }

  // reduce l across the 4 g-lanes (only cross-lane work in the kernel)
  #pragma unroll
  for (int qf_ = 0; qf_ < 4; ++qf_) {
    lacc[qf_] += __shfl_xor(lacc[qf_], 16);
    lacc[qf_] += __shfl_xor(lacc[qf_], 32);
  }

  // write UNNORMALIZED partials (bf16) + per-row l
  #pragma unroll
  for (int qf_ = 0; qf_ < 4; ++qf_) {
    #pragma unroll
    for (int r = 0; r < 4; ++r) {
      int row = q0 + qf_*16 + g*4 + r;
      #pragma unroll
      for (int vf = 0; vf < 4; ++vf) {
        int col = h*64 + vf*16 + fr;
        Opart[((size_t)part * 2048 + row) * 1024 + col] = f2bf(oacc[qf_][vf][r]);
      }
    }
  }
  if (g == 0) {
    size_t base = ((size_t)part * 16 + h) * 2048;
    #pragma unroll
    for (int qf_ = 0; qf_ < 4; ++qf_)
      Lpart[base + q0 + qf_*16 + fr] = lacc[qf_];
  }
}

// ---------------- merge the 2 KV-splits -> Ctx bf16 ----------------
// Fixed shared max => merged = (O0 + O1) / (l0 + l1)
__global__ __launch_bounds__(256) void mqa_merge(
    const u16* __restrict__ Opart, const float* __restrict__ Lpart,
    u16* __restrict__ Ctx)
{
  int idx = blockIdx.x * 256 + threadIdx.x;       // [0, 2*2048*256)
  int cg  = idx & 255;
  int row = (idx >> 8) & 2047;
  int b   = idx >> 19;
  int h   = cg >> 4;
  size_t mb0 = ((size_t)(b*2 + 0) * 16 + h) * 2048 + row;
  size_t mb1 = ((size_t)(b*2 + 1) * 16 + h) * 2048 + row;
  float rl = 1.f / (Lpart[mb0] + Lpart[mb1]);
  size_t o0 = ((size_t)(b*2 + 0) * 2048 + row) * 1024 + cg * 4;
  size_t o1 = ((size_t)(b*2 + 1) * 2048 + row) * 1024 + cg * 4;
  ushort4 a = *(const ushort4*)&Opart[o0];
  ushort4 c = *(const ushort4*)&Opart[o1];
  u16 o[4];
  o[0] = f2bf((bf2f(a.x) + bf2f(c.x)) * rl);
  o[1] = f2bf((bf2f(a.y) + bf2f(c.y)) * rl);
  o[2] = f2bf((bf2f(a.z) + bf2f(c.z)) * rl);
  o[3] = f2bf((bf2f(a.w) + bf2f(c.w)) * rl);
  *(ushort4*)&Ctx[((size_t)b * 2048 + row) * 1024 + cg * 4] = *(ushort4*)o;
}

extern "C" void kernel_launch(void* const* d_in, const int* in_sizes, int n_in,
                              void* d_out, int out_size, void* d_ws, size_t ws_size,
                              hipStream_t stream)
{
  const float* Qin = (const float*)d_in[0];
  const float* Wq  = (const float*)d_in[1];
  const float* Wk  = (const float*)d_in[2];
  const float* Wv  = (const float*)d_in[3];
  const float* Wo  = (const float*)d_in[4];
  float* out = (float*)d_out;

  u16* Xb  = (u16*)d_ws;                 // 4096*1024   Q_input bf16
  u16* WT  = Xb  + (size_t)4096*1024;    // 1152*1024   [Wq^T; Wk^T; Wv^T]
  u16* WoT = WT  + (size_t)1152*1024;    // 1024*1024   Wo^T
  u16* Qb  = WoT + (size_t)1024*1024;    // 4096*1024   Q proj
  u16* Kb  = Qb  + (size_t)4096*1024;    // 4096*64     K proj
  u16* Vtb = Kb  + (size_t)4096*64;      // 2*64*2048   V^T proj (k-permuted)
  u16* Ctx = Vtb + (size_t)2*64*2048;    // 4096*1024   attention out
  float* Lpart = (float*)(Ctx + (size_t)4096*1024);   // 4*16*2048

  // Opart (bf16, 4 parts x 2048 x 1024 = exactly out bytes) aliases d_out;
  // gemm2 overwrites d_out afterwards in stream order.
  u16* Opart = (u16*)d_out;

  mqa_cvt<<<2048, 256, 0, stream>>>(Qin, Xb, 4096*1024/8);
  mqa_tcvt4<<<2176, 256, 0, stream>>>(Wq, Wk, Wv, Wo, WT, WoT);

  mqa_gemm<1><<<64*9, 256, 0, stream>>>(Xb, WT, nullptr, Qb, Kb, Vtb,
                                        4096, 1152, 1024, 9);
  mqa_attn<<<dim3(8,16,4), 256, 0, stream>>>(Qb, Kb, Vtb, Opart, Lpart);
  mqa_merge<<<4096, 256, 0, stream>>>(Opart, Lpart, Ctx);
  mqa_gemm<0><<<64*8, 256, 0, stream>>>(Ctx, WoT, out, nullptr, nullptr, nullptr,
                                        4096, 1024, 1024, 8);
}

// Round 8
// 101.704 us; speedup vs baseline: 1.1265x; 1.1265x over previous
//
#include <hip/hip_runtime.h>

typedef __attribute__((ext_vector_type(8))) short bf16x8;
typedef __attribute__((ext_vector_type(4))) float f32x4;
typedef __attribute__((ext_vector_type(4))) unsigned int u32x4;
typedef unsigned short u16;

#define MFMA16(a,b,c) __builtin_amdgcn_mfma_f32_16x16x32_bf16((a),(b),(c),0,0,0)

__device__ __forceinline__ u16 f2bf(float f){
  unsigned int u = __float_as_uint(f);
  u += 0x7fffu + ((u >> 16) & 1u);
  return (u16)(u >> 16);
}
__device__ __forceinline__ float bf2f(u16 v){
  return __uint_as_float(((unsigned int)v) << 16);
}
__device__ __forceinline__ unsigned int cvtpk(float lo, float hi){
  unsigned int r;
  asm("v_cvt_pk_bf16_f32 %0, %1, %2" : "=v"(r) : "v"(lo), "v"(hi));
  return r;
}
__device__ __forceinline__ void gload16(const void* g, void* l){
  __builtin_amdgcn_global_load_lds(
      (__attribute__((address_space(1))) void*)g,
      (__attribute__((address_space(3))) void*)l, 16, 0, 0);
}

// ---------------- prepass: fp32 -> bf16 flat convert ----------------
__global__ __launch_bounds__(256) void mqa_cvt(const float* __restrict__ in,
                                               u16* __restrict__ out, int n8){
  int i = blockIdx.x * 256 + threadIdx.x;
  if (i >= n8) return;
  const float4* p = (const float4*)in;
  float4 a = p[2*i], b = p[2*i+1];
  u16 o[8] = { f2bf(a.x), f2bf(a.y), f2bf(a.z), f2bf(a.w),
               f2bf(b.x), f2bf(b.y), f2bf(b.z), f2bf(b.w) };
  *(bf16x8*)&out[(size_t)i*8] = *(bf16x8*)o;
}

// ---------------- prepass: all 4 weight transposes in ONE launch ----------
__global__ __launch_bounds__(256) void mqa_tcvt4(
    const float* __restrict__ Wq, const float* __restrict__ Wk,
    const float* __restrict__ Wv, const float* __restrict__ Wo,
    u16* __restrict__ WT, u16* __restrict__ WoT)
{
  __shared__ float t[32][33];
  int bx = blockIdx.x;
  const float* src; u16* dst; int C, cb, rb;
  if (bx < 1024)      { src = Wq; dst = WT;                      C = 1024; int q = bx;        cb = q & 31; rb = q >> 5; }
  else if (bx < 1088) { src = Wk; dst = WT + (size_t)1024*1024;  C = 64;   int q = bx - 1024; cb = q & 1;  rb = q >> 1; }
  else if (bx < 1152) { src = Wv; dst = WT + (size_t)1088*1024;  C = 64;   int q = bx - 1088; cb = q & 1;  rb = q >> 1; }
  else                { src = Wo; dst = WoT;                     C = 1024; int q = bx - 1152; cb = q & 31; rb = q >> 5; }
  int c0 = cb * 32, r0 = rb * 32;
  int x = threadIdx.x & 31, y0 = threadIdx.x >> 5;
  #pragma unroll
  for (int yy = y0; yy < 32; yy += 8)
    t[yy][x] = src[(size_t)(r0 + yy) * C + c0 + x];
  __syncthreads();
  #pragma unroll
  for (int yy = y0; yy < 32; yy += 8)
    dst[(size_t)(c0 + yy) * 1024 + r0 + x] = f2bf(t[x][yy]);
}

// ---------------- GEMM: A[M][K] bf16 row-major, Bt[N][K] bf16 row-major ----
// BM=64, BN=128, BK=64, double-buffered LDS, ONE barrier+drain per K-step.
// LDS XOR-swizzled (linear gload_lds dest + pre-swizzled GLOBAL source col,
// matching swizzle on the ds_read index) to avoid the 64-col row-stride
// bank conflict.  EPI 0: fp32 out.  EPI 1: QKV scatter (V k-permuted).
template<int EPI>
__global__ __launch_bounds__(256, 3) void mqa_gemm(
    const u16* __restrict__ A, const u16* __restrict__ Bt,
    float* __restrict__ outF, u16* __restrict__ Qb, u16* __restrict__ Kb,
    u16* __restrict__ Vtb, int M, int N, int K, int NT)
{
  __shared__ __align__(16) u16 lds_a[2][64*64];
  __shared__ __align__(16) u16 lds_b[2][128*64];
  int bx = blockIdx.x;
  int mt = bx / NT, nt = bx % NT;
  int m0 = mt * 64, n0 = nt * 128;
  int tid = threadIdx.x;
  int wid = tid >> 6, lane = tid & 63;
  int wr = (wid >> 1) * 32, wc = (wid & 1) * 64;
  int srow = lane >> 3;                 // staging: row within 8-row group
  int scol = ((lane & 7) ^ srow) * 8;   // pre-swizzled source col (8 bf16=16B)
  int fr = lane & 15, g = lane >> 4, fg = lane >> 4;
  int sw = fr & 7;                      // read-side swizzle key

  f32x4 acc[2][4];
  #pragma unroll
  for (int i = 0; i < 2; ++i)
    #pragma unroll
    for (int j = 0; j < 4; ++j) acc[i][j] = (f32x4)0.f;

  // stage one 64x64 A + 128x64 B tile into buffer `bi` (12 chunks of 16x64,
  // 2 instrs each; wave w stages chunks 3w..3w+2)
  auto stage = [&](int bi, int k0){
    #pragma unroll
    for (int cc = 0; cc < 3; ++cc) {
      int c = 3*wid + cc;
      #pragma unroll
      for (int j = 0; j < 2; ++j) {
        if (c < 4) {
          int row = c*16 + j*8;
          gload16(&A [(size_t)(m0 + row + srow) * K + k0 + scol], &lds_a[bi][row*64]);
        } else {
          int row = (c-4)*16 + j*8;
          gload16(&Bt[(size_t)(n0 + row + srow) * K + k0 + scol], &lds_b[bi][row*64]);
        }
      }
    }
  };

  stage(0, 0);
  __syncthreads();
  int cur = 0;
  for (int k0 = 0; k0 < K; k0 += 64) {
    if (k0 + 64 < K) stage(cur ^ 1, k0 + 64);
    #pragma unroll
    for (int ks = 0; ks < 2; ++ks) {
      bf16x8 af[2], bfr[4];
      #pragma unroll
      for (int i = 0; i < 2; ++i)
        af[i] = *(const bf16x8*)&lds_a[cur][(wr + i*16 + fr)*64 + (((ks*4+g) ^ sw))*8];
      #pragma unroll
      for (int j = 0; j < 4; ++j)
        bfr[j] = *(const bf16x8*)&lds_b[cur][(wc + j*16 + fr)*64 + (((ks*4+g) ^ sw))*8];
      #pragma unroll
      for (int i = 0; i < 2; ++i)
        #pragma unroll
        for (int j = 0; j < 4; ++j)
          acc[i][j] = MFMA16(af[i], bfr[j], acc[i][j]);
    }
    __syncthreads();   // drains vmcnt: next buffer staged; this buffer read-done
    cur ^= 1;
  }

  #pragma unroll
  for (int i = 0; i < 2; ++i) {
    #pragma unroll
    for (int j = 0; j < 4; ++j) {
      int ncol = n0 + wc + j*16 + fr;
      #pragma unroll
      for (int r = 0; r < 4; ++r) {
        int m = m0 + wr + i*16 + fg*4 + r;
        float v = acc[i][j][r];
        if (EPI == 0) {
          outF[(size_t)m * N + ncol] = v;
        } else {
          u16 bv = f2bf(v);
          if (ncol < 1024) {
            Qb[(size_t)m * 1024 + ncol] = bv;              // Q [B,S,H*HD]
          } else if (ncol < 1088) {
            Kb[(size_t)m * 64 + (ncol - 1024)] = bv;       // K [B,S,HD]
          } else {
            int b = m >> 11, s = m & 2047;                 // Vp [B,HD,S-perm]
            int k = s & 63;
            int pos = (k & 35) | ((k & 12) << 1) | ((k & 16) >> 2);
            Vtb[((size_t)b * 64 + (ncol - 1088)) * 2048 + (s & ~63) + pos] = bv;
          }
        }
      }
    }
  }
}

// ---------------- flash MQA attention ----------------
// swapped-QK^T (P in-register), FIXED-MAX softmax, 32 q-rows/wave,
// K/V double-buffered LDS via global_load_lds (XOR-swizzled), KV-split x2,
// 4 blocks/CU co-residency.  grid (S/128, H, B*2).
__global__ __launch_bounds__(256, 4) void mqa_attn(
    const u16* __restrict__ Qb, const u16* __restrict__ Kb,
    const u16* __restrict__ Vtb, u16* __restrict__ Opart,
    float* __restrict__ Lpart)
{
  const float C1 = 0.18033688011112042f;  // (1/8) * log2(e)
  const float MC = 32.f * C1;             // fixed max: raw score 32 (~9.4 sigma)
  int qt = blockIdx.x, h = blockIdx.y;
  int b = blockIdx.z >> 1, sp = blockIdx.z & 1;
  int part = blockIdx.z;
  int tid = threadIdx.x, wid = tid >> 6, lane = tid & 63;
  int fr = lane & 15, g = lane >> 4;
  int q0 = qt * 128 + wid * 32;

  // [buf][64 rows][64 cols] bf16, 8KB each; cols stored col16^(row&7) swizzled
  __shared__ __align__(16) u16 KT[2][64*64];
  __shared__ __align__(16) u16 VT[2][64*64];

  const u16* Qbase = Qb + (size_t)b * 2048 * 1024 + (size_t)h * 64;
  const u16* Kbase = Kb + (size_t)b * 2048 * 64;
  const u16* Vbase = Vtb + (size_t)b * 64 * 2048;

  // staging: wave stages rows [wid*16,+16) via 2 instrs (8 rows each);
  // lane l -> row_in_8 = l>>3, src col16 = (l&7)^(l>>3)  (dest is linear)
  int srow = lane >> 3;
  int scol = ((lane & 7) ^ srow) * 8;

  // Q as the MFMA B-operand: lane(fr,g) slot j = Q[q = qf*16+fr][d = ks*32+g*8+j]
  bf16x8 qfv[2][2];
  #pragma unroll
  for (int qf_ = 0; qf_ < 2; ++qf_)
    #pragma unroll
    for (int ks = 0; ks < 2; ++ks)
      qfv[qf_][ks] = *(const bf16x8*)&Qbase[(size_t)(q0 + qf_*16 + fr) * 1024 + ks*32 + g*8];

  f32x4 oacc[2][4];
  #pragma unroll
  for (int qf_ = 0; qf_ < 2; ++qf_)
    #pragma unroll
    for (int vf = 0; vf < 4; ++vf) oacc[qf_][vf] = (f32x4)0.f;
  float lacc0 = 0.f, lacc1 = 0.f;   // lane-local denominators; reduced ONCE at end

  const int kb0 = sp * 16;

  // prologue: stage tile kb0 into buf 0
  #pragma unroll
  for (int j = 0; j < 2; ++j) {
    int row = wid*16 + j*8 + srow;
    gload16(&Kbase[(size_t)(kb0*64 + row) * 64 + scol], &KT[0][(wid*16 + j*8) * 64]);
    gload16(&Vbase[(size_t)row * 2048 + kb0*64 + scol], &VT[0][(wid*16 + j*8) * 64]);
  }
  __syncthreads();

  int cur = 0;
  for (int kb = kb0; kb < kb0 + 16; ++kb) {
    // stage next tile into buf cur^1 (last iter: harmless re-stage of kb0)
    int ntl = (kb + 1 < kb0 + 16) ? kb + 1 : kb0;
    #pragma unroll
    for (int j = 0; j < 2; ++j) {
      int row = wid*16 + j*8 + srow;
      gload16(&Kbase[(size_t)(ntl*64 + row) * 64 + scol], &KT[cur^1][(wid*16 + j*8) * 64]);
      gload16(&Vbase[(size_t)row * 2048 + ntl*64 + scol], &VT[cur^1][(wid*16 + j*8) * 64]);
    }

    const u16* kc = &KT[cur][0];
    const u16* vc = &VT[cur][0];

    f32x4 sacc[2][4];
    #pragma unroll
    for (int qf_ = 0; qf_ < 2; ++qf_)
      #pragma unroll
      for (int kf = 0; kf < 4; ++kf) sacc[qf_][kf] = (f32x4)0.f;

    // S^T = K Q^T : lane(fr,g) gets S[k = kf*16+g*4+r][q = qf*16+fr]
    __builtin_amdgcn_s_setprio(1);
    #pragma unroll
    for (int ks = 0; ks < 2; ++ks) {
      #pragma unroll
      for (int kf = 0; kf < 4; ++kf) {
        bf16x8 kfr = *(const bf16x8*)&kc[(kf*16 + fr)*64 + (((ks*4+g) ^ (fr&7)))*8];
        sacc[0][kf] = MFMA16(kfr, qfv[0][ks], sacc[0][kf]);
        sacc[1][kf] = MFMA16(kfr, qfv[1][ks], sacc[1][kf]);
      }
    }
    __builtin_amdgcn_s_setprio(0);

    // P = exp2(s*C1 - MC), packed to bf16 PV A-frags; all lane-local
    unsigned int pk0[8], pk1[8];
    float s0 = 0.f, s1 = 0.f;
    #pragma unroll
    for (int kf = 0; kf < 4; ++kf) {
      float a0 = __builtin_amdgcn_exp2f(sacc[0][kf][0] * C1 - MC);
      float a1 = __builtin_amdgcn_exp2f(sacc[0][kf][1] * C1 - MC);
      float a2 = __builtin_amdgcn_exp2f(sacc[0][kf][2] * C1 - MC);
      float a3 = __builtin_amdgcn_exp2f(sacc[0][kf][3] * C1 - MC);
      s0 += (a0 + a1) + (a2 + a3);
      pk0[2*kf]   = cvtpk(a0, a1);
      pk0[2*kf+1] = cvtpk(a2, a3);
      float b0 = __builtin_amdgcn_exp2f(sacc[1][kf][0] * C1 - MC);
      float b1 = __builtin_amdgcn_exp2f(sacc[1][kf][1] * C1 - MC);
      float b2 = __builtin_amdgcn_exp2f(sacc[1][kf][2] * C1 - MC);
      float b3 = __builtin_amdgcn_exp2f(sacc[1][kf][3] * C1 - MC);
      s1 += (b0 + b1) + (b2 + b3);
      pk1[2*kf]   = cvtpk(b0, b1);
      pk1[2*kf+1] = cvtpk(b2, b3);
    }
    lacc0 += s0;
    lacc1 += s1;

    // ctx += P V : A = packed P (slot k-order matches V's stored permutation)
    __builtin_amdgcn_s_setprio(1);
    #pragma unroll
    for (int ks2 = 0; ks2 < 2; ++ks2) {
      u32x4 w0 = { pk0[4*ks2], pk0[4*ks2+1], pk0[4*ks2+2], pk0[4*ks2+3] };
      u32x4 w1 = { pk1[4*ks2], pk1[4*ks2+1], pk1[4*ks2+2], pk1[4*ks2+3] };
      bf16x8 pA0 = __builtin_bit_cast(bf16x8, w0);
      bf16x8 pA1 = __builtin_bit_cast(bf16x8, w1);
      #pragma unroll
      for (int vf = 0; vf < 4; ++vf) {
        bf16x8 vfr = *(const bf16x8*)&vc[(vf*16 + fr)*64 + (((ks2*4+g) ^ (fr&7)))*8];
        oacc[0][vf] = MFMA16(pA0, vfr, oacc[0][vf]);
        oacc[1][vf] = MFMA16(pA1, vfr, oacc[1][vf]);
      }
    }
    __builtin_amdgcn_s_setprio(0);

    __syncthreads();   // drains vmcnt(0): next tile staged; buf reads done
    cur ^= 1;
  }

  // reduce l across the 4 g-lanes (only cross-lane work in the kernel)
  lacc0 += __shfl_xor(lacc0, 16); lacc0 += __shfl_xor(lacc0, 32);
  lacc1 += __shfl_xor(lacc1, 16); lacc1 += __shfl_xor(lacc1, 32);

  // write UNNORMALIZED partials (bf16) + per-row l
  #pragma unroll
  for (int qf_ = 0; qf_ < 2; ++qf_) {
    #pragma unroll
    for (int r = 0; r < 4; ++r) {
      int row = q0 + qf_*16 + g*4 + r;
      #pragma unroll
      for (int vf = 0; vf < 4; ++vf) {
        int col = h*64 + vf*16 + fr;
        Opart[((size_t)part * 2048 + row) * 1024 + col] = f2bf(oacc[qf_][vf][r]);
      }
    }
  }
  if (g == 0) {
    int q = q0 + fr;
    size_t base = ((size_t)part * 16 + h) * 2048;
    Lpart[base + q]      = lacc0;
    Lpart[base + q + 16] = lacc1;
  }
}

// ---------------- merge the 2 KV-splits -> Ctx bf16 ----------------
// Fixed shared max => merged = (O0 + O1) / (l0 + l1)
__global__ __launch_bounds__(256) void mqa_merge(
    const u16* __restrict__ Opart, const float* __restrict__ Lpart,
    u16* __restrict__ Ctx)
{
  int idx = blockIdx.x * 256 + threadIdx.x;       // [0, 2*2048*256)
  int cg  = idx & 255;
  int row = (idx >> 8) & 2047;
  int b   = idx >> 19;
  int h   = cg >> 4;
  size_t mb0 = ((size_t)(b*2 + 0) * 16 + h) * 2048 + row;
  size_t mb1 = ((size_t)(b*2 + 1) * 16 + h) * 2048 + row;
  float rl = 1.f / (Lpart[mb0] + Lpart[mb1]);
  size_t o0 = ((size_t)(b*2 + 0) * 2048 + row) * 1024 + cg * 4;
  size_t o1 = ((size_t)(b*2 + 1) * 2048 + row) * 1024 + cg * 4;
  ushort4 a = *(const ushort4*)&Opart[o0];
  ushort4 c = *(const ushort4*)&Opart[o1];
  u16 o[4];
  o[0] = f2bf((bf2f(a.x) + bf2f(c.x)) * rl);
  o[1] = f2bf((bf2f(a.y) + bf2f(c.y)) * rl);
  o[2] = f2bf((bf2f(a.z) + bf2f(c.z)) * rl);
  o[3] = f2bf((bf2f(a.w) + bf2f(c.w)) * rl);
  *(ushort4*)&Ctx[((size_t)b * 2048 + row) * 1024 + cg * 4] = *(ushort4*)o;
}

extern "C" void kernel_launch(void* const* d_in, const int* in_sizes, int n_in,
                              void* d_out, int out_size, void* d_ws, size_t ws_size,
                              hipStream_t stream)
{
  const float* Qin = (const float*)d_in[0];
  const float* Wq  = (const float*)d_in[1];
  const float* Wk  = (const float*)d_in[2];
  const float* Wv  = (const float*)d_in[3];
  const float* Wo  = (const float*)d_in[4];
  float* out = (float*)d_out;

  u16* Xb  = (u16*)d_ws;                 // 4096*1024   Q_input bf16
  u16* WT  = Xb  + (size_t)4096*1024;    // 1152*1024   [Wq^T; Wk^T; Wv^T]
  u16* WoT = WT  + (size_t)1152*1024;    // 1024*1024   Wo^T
  u16* Qb  = WoT + (size_t)1024*1024;    // 4096*1024   Q proj
  u16* Kb  = Qb  + (size_t)4096*1024;    // 4096*64     K proj
  u16* Vtb = Kb  + (size_t)4096*64;      // 2*64*2048   V^T proj (k-permuted)
  u16* Ctx = Vtb + (size_t)2*64*2048;    // 4096*1024   attention out
  float* Lpart = (float*)(Ctx + (size_t)4096*1024);   // 4*16*2048

  // Opart (bf16, 4 parts x 2048 x 1024 = exactly out bytes) aliases d_out;
  // gemm2 overwrites d_out afterwards in stream order.
  u16* Opart = (u16*)d_out;

  mqa_cvt<<<2048, 256, 0, stream>>>(Qin, Xb, 4096*1024/8);
  mqa_tcvt4<<<2176, 256, 0, stream>>>(Wq, Wk, Wv, Wo, WT, WoT);

  mqa_gemm<1><<<64*9, 256, 0, stream>>>(Xb, WT, nullptr, Qb, Kb, Vtb,
                                        4096, 1152, 1024, 9);
  mqa_attn<<<dim3(16,16,4), 256, 0, stream>>>(Qb, Kb, Vtb, Opart, Lpart);
  mqa_merge<<<4096, 256, 0, stream>>>(Opart, Lpart, Ctx);
  mqa_gemm<0><<<64*8, 256, 0, stream>>>(Ctx, WoT, out, nullptr, nullptr, nullptr,
                                        4096, 1024, 1024, 8);
}